// Round 13
// baseline (2321.840 us; speedup 1.0000x reference)
//
#include <hip/hip_runtime.h>

typedef unsigned int       u32;
typedef unsigned long long u64;

#define NB 4
#define NQ 8192
#define GH   1.5f
#define GINV (1.0f/1.5f)
#define GORG (-48.0f)
#define OVF_CAP 1024
// grid-path ws layout (bytes)
#define OFF_OVC 16777216ull                 // cellEnd: 16 segs * 262144 * 4
#define OFF_BS  16777472ull                 // ovfCnt 64B (+pad)
#define OFF_OVP 16793856ull                 // blockSums 4096*4
#define OFF_SP  17056000ull                 // ovfPts 16*1024*16
#define WS_GRID 18235648ull                 // spts 73728*16
#define ZERO_N4 1048592                     // (cellEnd+ovfCnt)/16
#define INFKEY  (0x7f800000ULL << 32)

__device__ __forceinline__ u64 umin64(u64 a, u64 b) { return a < b ? a : b; }
__device__ __forceinline__ u64 umax64(u64 a, u64 b) { return a > b ? a : b; }

// lexicographic (d, idx) insert into sorted triple; ties -> lower index
__device__ __forceinline__ void lexins(double& e0d, double& e1d, double& e2d,
                                       int& e0i, int& e1i, int& e2i,
                                       double d, int i) {
  if (d < e2d || (d == e2d && i < e2i)) {
    if (d < e0d || (d == e0d && i < e0i)) {
      e2d = e1d; e2i = e1i; e1d = e0d; e1i = e0i; e0d = d; e0i = i;
    } else if (d < e1d || (d == e1d && i < e1i)) {
      e2d = e1d; e2i = e1i; e1d = d; e1i = i;
    } else {
      e2d = d; e2i = i;
    }
  }
}

// point index decode: [a0:4x8192][a1:4x4096][a2:4x2048][a3:4x4096] = 73728
__device__ __forceinline__ void decode(int i, int& a, int& b, int& j, int& M) {
  if (i < 32768)      { a = 0; b = i >> 13; j = i & 8191; M = 8192; }
  else if (i < 49152) { int t = i - 32768; a = 1; b = t >> 12; j = t & 4095; M = 4096; }
  else if (i < 57344) { int t = i - 49152; a = 2; b = t >> 11; j = t & 2047; M = 2048; }
  else                { int t = i - 57344; a = 3; b = t >> 12; j = t & 4095; M = 4096; }
}
__device__ __forceinline__ int seg_ptbase(int a, int b, int M) {
  int ab = (a == 0) ? 0 : ((a == 1) ? 32768 : ((a == 2) ? 49152 : 57344));
  return ab + b * M;
}

// ---------------- build: zero -> hist -> scan(3) -> scatter -----------------
__global__ __launch_bounds__(256) void zero_kernel(uint4* __restrict__ p) {
  int i = blockIdx.x * 256 + threadIdx.x;
  if (i < ZERO_N4) p[i] = make_uint4(0, 0, 0, 0);
}

__global__ __launch_bounds__(256) void grid_hist(
    const float* __restrict__ k2p, const float* __restrict__ k3p,
    const float* __restrict__ k4p, const float* __restrict__ mmp,
    u32* __restrict__ cellEnd) {
  int i = blockIdx.x * 256 + threadIdx.x;
  if (i >= 73728) return;
  int a, b, j, M; decode(i, a, b, j, M);
  const float* src = (a == 0) ? k2p : ((a == 1) ? k3p : ((a == 2) ? k4p : mmp));
  const float* p = src + ((size_t)b * M + j) * 3;
  float x = p[0], y = p[1], z = p[2];
  if (fabsf(x) < 48.f && fabsf(y) < 48.f && fabsf(z) < 48.f) {
    int cx = min((int)((x - GORG) * GINV), 63);
    int cy = min((int)((y - GORG) * GINV), 63);
    int cz = min((int)((z - GORG) * GINV), 63);
    int seg = a * 4 + b;
    atomicAdd(cellEnd + (((size_t)seg) << 18) + ((cz << 12) | (cy << 6) | cx), 1u);
  }
}

// S1: 4096 blocks (16 segs x 256), 1024 cells/block: local exclusive scan
__global__ __launch_bounds__(256) void scan_local(
    u32* __restrict__ cellEnd, u32* __restrict__ blockSums) {
  __shared__ u32 lds[256];
  uint4* c = (uint4*)(cellEnd + ((size_t)(blockIdx.x >> 8) << 18) +
                      ((blockIdx.x & 255) << 10));
  int t = threadIdx.x;
  uint4 v = c[t];                       // coalesced 16B/lane
  u32 ts = v.x + v.y + v.z + v.w;
  lds[t] = ts;
  __syncthreads();
  for (int off = 1; off < 256; off <<= 1) {   // Hillis-Steele inclusive
    u32 a = (t >= off) ? lds[t - off] : 0;
    __syncthreads();
    lds[t] += a;
    __syncthreads();
  }
  u32 ex = t ? lds[t - 1] : 0;
  c[t] = make_uint4(ex, ex + v.x, ex + v.x + v.y, ex + v.x + v.y + v.z);
  if (t == 255) blockSums[blockIdx.x] = lds[255];
}

// S2: 16 blocks: exclusive scan of 256 block sums per segment
__global__ __launch_bounds__(256) void scan_block(u32* __restrict__ blockSums) {
  __shared__ u32 lds[256];
  u32* bs = blockSums + (blockIdx.x << 8);
  int t = threadIdx.x;
  lds[t] = bs[t];
  __syncthreads();
  for (int off = 1; off < 256; off <<= 1) {
    u32 a = (t >= off) ? lds[t - off] : 0;
    __syncthreads();
    lds[t] += a;
    __syncthreads();
  }
  bs[t] = t ? lds[t - 1] : 0;
}

// S3: add scanned block offsets -> cell START values
__global__ __launch_bounds__(256) void scan_add(
    u32* __restrict__ cellEnd, const u32* __restrict__ blockSums) {
  uint4* c = (uint4*)(cellEnd + ((size_t)(blockIdx.x >> 8) << 18) +
                      ((blockIdx.x & 255) << 10));
  u32 off = blockSums[blockIdx.x];
  int t = threadIdx.x;
  uint4 v = c[t];
  c[t] = make_uint4(v.x + off, v.y + off, v.z + off, v.w + off);
}

__global__ __launch_bounds__(256) void grid_scatter(
    const float* __restrict__ k2p, const float* __restrict__ k3p,
    const float* __restrict__ k4p, const float* __restrict__ mmp,
    u32* __restrict__ cellEnd, u32* __restrict__ ovfCnt,
    float4* __restrict__ ovfPts, float4* __restrict__ spts) {
  int i = blockIdx.x * 256 + threadIdx.x;
  if (i >= 73728) return;
  int a, b, j, M; decode(i, a, b, j, M);
  const float* src = (a == 0) ? k2p : ((a == 1) ? k3p : ((a == 2) ? k4p : mmp));
  const float* p = src + ((size_t)b * M + j) * 3;
  float x = p[0], y = p[1], z = p[2];
  int seg = a * 4 + b;
  if (fabsf(x) < 48.f && fabsf(y) < 48.f && fabsf(z) < 48.f) {
    int cx = min((int)((x - GORG) * GINV), 63);
    int cy = min((int)((y - GORG) * GINV), 63);
    int cz = min((int)((z - GORG) * GINV), 63);
    u32 pos = atomicAdd(cellEnd + (((size_t)seg) << 18) + ((cz << 12) | (cy << 6) | cx), 1u);
    spts[seg_ptbase(a, b, M) + pos] = make_float4(x, y, z, __int_as_float(j));
  } else {
    u32 o = atomicAdd(ovfCnt + seg, 1u);
    if (o < OVF_CAP) ovfPts[(seg << 10) + o] = make_float4(x, y, z, __int_as_float(j));
  }
}

// ---------------- grid search + epilogue ------------------------------------
__global__ __launch_bounds__(256, 2) void grid_search(
    const float* __restrict__ pts,
    const float* __restrict__ k2p, const float* __restrict__ f2,
    const float* __restrict__ k3p, const float* __restrict__ f3,
    const float* __restrict__ k4p, const float* __restrict__ f4,
    const float* __restrict__ mmp,
    const float* __restrict__ wfc, const float* __restrict__ wcls,
    const u32* __restrict__ cellEnd, const u32* __restrict__ ovfCnt,
    const float4* __restrict__ ovfPts, const float4* __restrict__ spts,
    float* __restrict__ out) {
  __shared__ float swv[96];
  __shared__ float spart[64][3];
  const int tid = threadIdx.x;
  const int b = blockIdx.y;
  const int qbase = blockIdx.x * 64;
  const int qi = tid & 63;
  const int task = __builtin_amdgcn_readfirstlane(tid >> 6);  // 0..2 NN, 3 mask
  const int gq = b * NQ + qbase + qi;

  if (tid >= 64 && tid < 160) {          // fold w_cls @ w_fc
    int t = tid - 64;
    float acc = 0.f;
    for (int j = 0; j < 64; ++j) acc += wcls[j] * wfc[j * 96 + t];
    swv[t] = acc;
  }

  const float qx = pts[3 * gq], qy = pts[3 * gq + 1], qz = pts[3 * gq + 2];
  const double qdx = (double)qx, qdy = (double)qy, qdz = (double)qz;
  const double qn_d = (qdx * qdx + qdy * qdy) + qdz * qdz;  // ref grouping
  const int cx = min(max((int)((fminf(fmaxf(qx, -48.f), 47.9f) - GORG) * GINV), 0), 63);
  const int cy = min(max((int)((fminf(fmaxf(qy, -48.f), 47.9f) - GORG) * GINV), 0), 63);
  const int cz = min(max((int)((fminf(fmaxf(qz, -48.f), 47.9f) - GORG) * GINV), 0), 63);

  const int Mt[4] = {8192, 4096, 2048, 4096};
  const int seg = task * 4 + b;
  const u32* ce = cellEnd + ((size_t)seg << 18);
  const float4* sp = spts + seg_ptbase(task, b, Mt[task]);
  const float4* op = ovfPts + (seg << 10);
  const u32 oc = min(ovfCnt[seg], (u32)OVF_CAP);

  u64 t6[6];
#pragma unroll
  for (int r = 0; r < 6; ++r) t6[r] = INFKEY;

  if (task < 3) {
    // DIRECT-DISTANCE prefilter key: kv = |q-k|^2 in f32 (err ~1e-5 since
    // coords cancel before squaring). kv>=0 -> bits monotone, u64-packable.
    // top-6 kept, f64-rescored with ref-exact grouping downstream.
    auto keyins = [&](float4 c) {
      float dx = qx - c.x, dy = qy - c.y, dz = qz - c.z;
      float kv = fmaf(dz, dz, fmaf(dy, dy, dx * dx));
      u64 kn = ((u64)__float_as_uint(kv) << 32) | (u32)__float_as_uint(c.w);
      if (kn < t6[5]) {
        u64 t;
        t = umax64(t6[0], kn); t6[0] = umin64(t6[0], kn); kn = t;
        t = umax64(t6[1], kn); t6[1] = umin64(t6[1], kn); kn = t;
        t = umax64(t6[2], kn); t6[2] = umin64(t6[2], kn); kn = t;
        t = umax64(t6[3], kn); t6[3] = umin64(t6[3], kn); kn = t;
        t = umax64(t6[4], kn); t6[4] = umin64(t6[4], kn); kn = t;
        t6[5] = umin64(t6[5], kn);
      }
    };
    auto runf = [&](u32 ps, u32 pe) {    // EXACT: no tail padding/duplicates
      u32 p = ps;
      for (; p + 4 <= pe; p += 4) {
        float4 cc[4];
#pragma unroll
        for (int u = 0; u < 4; ++u) cc[u] = sp[p + u];
#pragma unroll
        for (int u = 0; u < 4; ++u) keyins(cc[u]);
      }
      for (; p < pe; ++p) keyins(sp[p]);
    };
    for (u32 o = 0; o < oc; ++o) keyins(op[o]);   // out-of-grid: always scan
    int r = 0;
    while (true) {
      for (int dz = -r; dz <= r; ++dz) {          // shell r only (no revisit)
        int z = cz + dz; if ((unsigned)z > 63u) continue;
        for (int dy = -r; dy <= r; ++dy) {
          int y = cy + dy; if ((unsigned)y > 63u) continue;
          int rb = (z << 12) | (y << 6);
          bool edge = (dz == -r || dz == r || dy == -r || dy == r);
          if (edge) {
            int x0 = max(cx - r, 0), x1 = min(cx + r, 63);
            u32 pe = ce[rb + x1];
            u32 ps = (rb + x0) ? ce[rb + x0 - 1] : 0;
            runf(ps, pe);
          } else {
            int xl = cx - r;
            if (xl >= 0) { u32 pe = ce[rb + xl]; u32 ps = (rb + xl) ? ce[rb + xl - 1] : 0; runf(ps, pe); }
            int xr = cx + r;
            if (xr <= 63) { u32 pe = ce[rb + xr]; u32 ps = ce[rb + xr - 1]; runf(ps, pe); }
          }
        }
      }
      if (r >= 1) {
        // stop: 3rd-best key + margin <= dist^2 to nearest unscanned cell
        float d3f = __uint_as_float((u32)(t6[2] >> 32));   // inf if <3 found
        float m = 1e30f;
        if (cx - r > 0)  m = fminf(m, qx - (GORG + (cx - r) * GH));
        if (cx + r < 63) m = fminf(m, (GORG + (cx + r + 1) * GH) - qx);
        if (cy - r > 0)  m = fminf(m, qy - (GORG + (cy - r) * GH));
        if (cy + r < 63) m = fminf(m, (GORG + (cy + r + 1) * GH) - qy);
        if (cz - r > 0)  m = fminf(m, qz - (GORG + (cz - r) * GH));
        if (cz + r < 63) m = fminf(m, (GORG + (cz + r + 1) * GH) - qz);
        if (m > 0.f && d3f + 0.01f <= m * m) break;
      }
      if (r >= 63) break;
      ++r;
    }
  } else {
    // mask: any point < 0.5 m is within Chebyshev ring 1 (0.5 < GH) -> exact
    const double dm2x = -2.0 * qdx, dm2y = -2.0 * qdy, dm2z = -2.0 * qdz;
    double smin = 1e300;
    auto meval = [&](float4 c) {
      double x = (double)c.x, y = (double)c.y, z = (double)c.z;
      double kn = fma(z, z, fma(y, y, x * x));
      smin = fmin(smin, fma(dm2x, x, fma(dm2y, y, fma(dm2z, z, kn))));
    };
    for (u32 o = 0; o < oc; ++o) meval(op[o]);
    for (int dz = -1; dz <= 1; ++dz) {
      int z = cz + dz; if ((unsigned)z > 63u) continue;
      for (int dy = -1; dy <= 1; ++dy) {
        int y = cy + dy; if ((unsigned)y > 63u) continue;
        int rb = (z << 12) | (y << 6);
        int x0 = max(cx - 1, 0), x1 = min(cx + 1, 63);
        u32 pe = ce[rb + x1];
        u32 ps = (rb + x0) ? ce[rb + x0 - 1] : 0;
        for (u32 p = ps; p < pe; ++p) meval(sp[p]);
      }
    }
    out[NB * NQ + gq] = (qn_d + smin < 0.25) ? 1.0f : 0.0f;
  }
  __syncthreads();

  // epilogue: f64 rescore of top-6 members (ref-exact grouping), weights, FC
  if (tid < 192) {
    const float* kp = (task == 0) ? k2p : ((task == 1) ? k3p : k4p);
    const int    M  = Mt[task];
    double e0 = 1e300, e1 = 1e300, e2 = 1e300;
    int i0 = 0, i1 = 0, i2 = 0;
#pragma unroll
    for (int r = 0; r < 6; ++r) {
      if ((u32)(t6[r] >> 32) == 0x7f800000u) continue;   // skip empty slots
      int idx = (int)(u32)t6[r];
      const float* c = kp + ((size_t)b * M + idx) * 3;
      double x = (double)c[0], y = (double)c[1], z = (double)c[2];
      double kn2 = (x * x + y * y) + z * z;
      double dot = (qdx * x + qdy * y) + qdz * z;
      double d2 = (qn_d + kn2) - 2.0 * dot;
      lexins(e0, e1, e2, i0, i1, i2, d2, idx);
    }
    double d0 = fmax(e0, 0.0), d1 = fmax(e1, 0.0), d2v = fmax(e2, 0.0);
    double r0 = 1.0 / (d0 + 1e-8), r1 = 1.0 / (d1 + 1e-8), r2 = 1.0 / (d2v + 1e-8);
    double sum = (r0 + r1) + r2;
    float wa = (float)(r0 / sum), wb = (float)(r1 / sum), wc = (float)(r2 / sum);
    const float* fp = (task == 0) ? f2 : ((task == 1) ? f3 : f4);
    const float* g0 = fp + ((size_t)b * M + i0) * 32;
    const float* g1 = fp + ((size_t)b * M + i1) * 32;
    const float* g2 = fp + ((size_t)b * M + i2) * 32;
    float acc = 0.f;
#pragma unroll
    for (int wd = 0; wd < 32; ++wd) {
      float v = (wa * g0[wd] + wb * g1[wd]) + wc * g2[wd];
      acc += swv[task * 32 + wd] * v;
    }
    spart[qi][task] = acc;
  }
  __syncthreads();
  if (tid < 64) {
    out[b * NQ + qbase + tid] =
        (spart[tid][0] + spart[tid][1]) + spart[tid][2];
  }
}

// ---------------- brute fallback (r11-proven structure, no workspace) -------
__device__ __forceinline__ void ins4f(float kv, u32 idx,
                                      float& k0, float& k1, float& k2, float& k3,
                                      u32& i0, u32& i1, u32& i2, u32& i3) {
  if (kv < k3) {
    bool lt0 = kv < k0, lt1 = kv < k1, lt2 = kv < k2;
    k3 = lt2 ? k2 : kv;               i3 = lt2 ? i2 : idx;
    k2 = lt2 ? (lt1 ? k1 : kv) : k2;  i2 = lt2 ? (lt1 ? i1 : idx) : i2;
    k1 = lt1 ? (lt0 ? k0 : kv) : k1;  i1 = lt1 ? (lt0 ? i0 : idx) : i1;
    k0 = lt0 ? kv : k0;               i0 = lt0 ? idx : i0;
  }
}

__global__ __launch_bounds__(512, 2) void brute_kernel(
    const float* __restrict__ pts,
    const float* __restrict__ k2p, const float* __restrict__ f2,
    const float* __restrict__ k3p, const float* __restrict__ f3,
    const float* __restrict__ k4p, const float* __restrict__ f4,
    const float* __restrict__ mmp,
    const float* __restrict__ wfc, const float* __restrict__ wcls,
    float* __restrict__ out) {
  __shared__ double sqn[64];
  __shared__ float dk[3][64][4][4];
  __shared__ u32 di[3][64][4][4];
  __shared__ double mmin[64][8];
  __shared__ float swv[96];
  __shared__ float spart[64][3];
  const int tid = threadIdx.x;
  const int b = blockIdx.y;
  const int q0 = blockIdx.x * 64;
  const int qloc = tid & 63;
  const int wid = __builtin_amdgcn_readfirstlane(tid >> 6);
  if (tid >= 64 && tid < 160) {
    int t = tid - 64;
    float acc = 0.f;
    for (int j = 0; j < 64; ++j) acc += wcls[j] * wfc[j * 96 + t];
    swv[t] = acc;
  }
  int gq = b * NQ + q0 + qloc;
  float qx = pts[3 * gq], qy = pts[3 * gq + 1], qz = pts[3 * gq + 2];
  double qdx = qx, qdy = qy, qdz = qz;
  double qn = (qdx * qdx + qdy * qdy) + qdz * qdz;
  if (tid < 64) sqn[tid] = qn;
  float m2x = -2.f * qx, m2y = -2.f * qy, m2z = -2.f * qz;
  double dm2x = -2.0 * qdx, dm2y = -2.0 * qdy, dm2z = -2.0 * qdz;
  {
    int lvl, prt, gs, gl;
    if (wid < 4)      { lvl = 0; prt = wid;     gs = wid * 2048;       gl = 2048; }
    else if (wid < 6) { lvl = 1; prt = wid - 4; gs = (wid - 4) * 2048; gl = 2048; }
    else              { lvl = 2; prt = wid - 6; gs = (wid - 6) * 1024; gl = 1024; }
    const float* raw = ((lvl == 0) ? k2p : ((lvl == 1) ? k3p : k4p)) +
                       (size_t)b * ((lvl == 0) ? 8192 : ((lvl == 1) ? 4096 : 2048)) * 3;
    float k0 = __builtin_inff(), k1 = k0, k2 = k0, k3 = k0;
    u32 i0 = 0, i1 = 0, i2 = 0, i3 = 0;
    for (int j = 0; j < gl; j += 8) {
      float key[8];
#pragma unroll
      for (int u = 0; u < 8; ++u) {
        const float* p = raw + (size_t)(gs + j + u) * 3;
        float x = p[0], y = p[1], z = p[2];
        float n2 = fmaf(z, z, fmaf(y, y, x * x));
        key[u] = fmaf(m2x, x, fmaf(m2y, y, fmaf(m2z, z, n2)));
      }
#pragma unroll
      for (int u = 0; u < 8; ++u)
        ins4f(key[u], (u32)(gs + j + u), k0, k1, k2, k3, i0, i1, i2, i3);
    }
    int pr = (lvl == 0) ? prt : prt;
    dk[lvl][qloc][pr][0] = k0; di[lvl][qloc][pr][0] = i0;
    dk[lvl][qloc][pr][1] = k1; di[lvl][qloc][pr][1] = i1;
    dk[lvl][qloc][pr][2] = k2; di[lvl][qloc][pr][2] = i2;
    dk[lvl][qloc][pr][3] = k3; di[lvl][qloc][pr][3] = i3;
    int ms = (wid < 6) ? wid * 256 : 1536 + (wid - 6) * 1280;
    int ml = (wid < 6) ? 256 : 1280;
    const float* mr = mmp + (size_t)b * 4096 * 3;
    double smin = 1e300;
    for (int j = 0; j < ml; ++j) {
      const float* p = mr + (size_t)(ms + j) * 3;
      double x = p[0], y = p[1], z = p[2];
      double kn = fma(z, z, fma(y, y, x * x));
      smin = fmin(smin, fma(dm2x, x, fma(dm2y, y, fma(dm2z, z, kn))));
    }
    mmin[qloc][wid] = smin;
  }
  __syncthreads();
  if (tid < 192) {
    int lvl = __builtin_amdgcn_readfirstlane(tid >> 6);
    int q = tid & 63;
    const float* kp = (lvl == 0) ? k2p : ((lvl == 1) ? k3p : k4p);
    int M = (lvl == 0) ? 8192 : ((lvl == 1) ? 4096 : 2048);
    int np = (lvl == 0) ? 4 : 2;
    double qn2 = sqn[q];
    const float* qp2 = pts + 3 * (b * NQ + q0 + q);
    double ax = qp2[0], ay = qp2[1], az = qp2[2];
    double e0 = 1e300, e1 = 1e300, e2 = 1e300;
    int i0 = 0, i1 = 0, i2 = 0;
    for (int h = 0; h < np; ++h)
#pragma unroll
      for (int r = 0; r < 4; ++r) {
        int idx = (int)di[lvl][q][h][r];
        const float* c = kp + ((size_t)b * M + idx) * 3;
        double x = c[0], y = c[1], z = c[2];
        double kn2 = (x * x + y * y) + z * z;
        double dot = (ax * x + ay * y) + az * z;
        lexins(e0, e1, e2, i0, i1, i2, (qn2 + kn2) - 2.0 * dot, idx);
      }
    double d0 = fmax(e0, 0.0), d1 = fmax(e1, 0.0), d2v = fmax(e2, 0.0);
    double r0 = 1.0 / (d0 + 1e-8), r1 = 1.0 / (d1 + 1e-8), r2 = 1.0 / (d2v + 1e-8);
    double sum = (r0 + r1) + r2;
    float wa = (float)(r0 / sum), wb = (float)(r1 / sum), wc = (float)(r2 / sum);
    const float* fp = (lvl == 0) ? f2 : ((lvl == 1) ? f3 : f4);
    const float* g0 = fp + ((size_t)b * M + i0) * 32;
    const float* g1 = fp + ((size_t)b * M + i1) * 32;
    const float* g2 = fp + ((size_t)b * M + i2) * 32;
    float acc = 0.f;
#pragma unroll
    for (int wd = 0; wd < 32; ++wd)
      acc += swv[lvl * 32 + wd] * ((wa * g0[wd] + wb * g1[wd]) + wc * g2[wd]);
    spart[q][lvl] = acc;
  } else if (tid < 256) {
    int q = tid - 192;
    double sm = mmin[q][0];
#pragma unroll
    for (int p = 1; p < 8; ++p) sm = fmin(sm, mmin[q][p]);
    out[NB * NQ + b * NQ + q0 + q] = (sqn[q] + sm < 0.25) ? 1.0f : 0.0f;
  }
  __syncthreads();
  if (tid < 64)
    out[b * NQ + q0 + tid] = (spart[tid][0] + spart[tid][1]) + spart[tid][2];
}

extern "C" void kernel_launch(void* const* d_in, const int* in_sizes, int n_in,
                              void* d_out, int out_size, void* d_ws, size_t ws_size,
                              hipStream_t stream) {
  const float* pts    = (const float*)d_in[0];
  const float* known2 = (const float*)d_in[1];
  const float* feats2 = (const float*)d_in[2];
  const float* known3 = (const float*)d_in[3];
  const float* feats3 = (const float*)d_in[4];
  const float* known4 = (const float*)d_in[5];
  const float* feats4 = (const float*)d_in[6];
  const float* match  = (const float*)d_in[7];
  const float* wfc    = (const float*)d_in[8];
  const float* wcls   = (const float*)d_in[9];

  if (ws_size >= WS_GRID) {
    char* ws = (char*)d_ws;
    u32*    cellEnd   = (u32*)ws;
    u32*    ovfCnt    = (u32*)(ws + OFF_OVC);
    u32*    blockSums = (u32*)(ws + OFF_BS);
    float4* ovfPts    = (float4*)(ws + OFF_OVP);
    float4* spts      = (float4*)(ws + OFF_SP);
    hipLaunchKernelGGL(zero_kernel, dim3(4097), dim3(256), 0, stream, (uint4*)ws);
    hipLaunchKernelGGL(grid_hist, dim3(288), dim3(256), 0, stream,
                       known2, known3, known4, match, cellEnd);
    hipLaunchKernelGGL(scan_local, dim3(4096), dim3(256), 0, stream,
                       cellEnd, blockSums);
    hipLaunchKernelGGL(scan_block, dim3(16), dim3(256), 0, stream, blockSums);
    hipLaunchKernelGGL(scan_add, dim3(4096), dim3(256), 0, stream,
                       cellEnd, blockSums);
    hipLaunchKernelGGL(grid_scatter, dim3(288), dim3(256), 0, stream,
                       known2, known3, known4, match,
                       cellEnd, ovfCnt, ovfPts, spts);
    hipLaunchKernelGGL(grid_search, dim3(128, NB), dim3(256), 0, stream,
                       pts, known2, feats2, known3, feats3, known4, feats4,
                       match, wfc, wcls, cellEnd, ovfCnt, ovfPts, spts,
                       (float*)d_out);
  } else {
    hipLaunchKernelGGL(brute_kernel, dim3(128, NB), dim3(512), 0, stream,
                       pts, known2, feats2, known3, feats3, known4, feats4,
                       match, wfc, wcls, (float*)d_out);
  }
}

// Round 14
// 2285.907 us; speedup vs baseline: 1.0157x; 1.0157x over previous
//
#include <hip/hip_runtime.h>

typedef unsigned int       u32;
typedef unsigned long long u64;

#define NB 4
#define NQ 8192
#define GH   1.5f
#define GINV (1.0f/1.5f)
#define GORG (-48.0f)
#define OVF_CAP 1024
// grid-path ws layout (bytes): 20 segs = 16 candidate + 4 query
#define OFF_OVC 20971520ull                 // cellEnd: 20 * 262144 * 4
#define OFF_BS  20971648ull                 // ovfCnt 80B (+pad)
#define OFF_OVP 20992128ull                 // blockSums 5120*4
#define OFF_SP  21319808ull                 // ovfPts 20*1024*16
#define OFF_QP  22499456ull                 // spts 73728*16
#define WS_GRID 23023744ull                 // qspts 32768*16
#define ZERO_N4 1310728                     // (cellEnd+ovfCnt)/16
#define INFKEY  (0x7f800000ULL << 32)

__device__ __forceinline__ u64 umin64(u64 a, u64 b) { return a < b ? a : b; }
__device__ __forceinline__ u64 umax64(u64 a, u64 b) { return a > b ? a : b; }

// lexicographic (d, idx) insert into sorted triple; ties -> lower index
__device__ __forceinline__ void lexins(double& e0d, double& e1d, double& e2d,
                                       int& e0i, int& e1i, int& e2i,
                                       double d, int i) {
  if (d < e2d || (d == e2d && i < e2i)) {
    if (d < e0d || (d == e0d && i < e0i)) {
      e2d = e1d; e2i = e1i; e1d = e0d; e1i = e0i; e0d = d; e0i = i;
    } else if (d < e1d || (d == e1d && i < e1i)) {
      e2d = e1d; e2i = e1i; e1d = d; e1i = i;
    } else {
      e2d = d; e2i = i;
    }
  }
}

// item decode: [a0:4x8192][a1:4x4096][a2:4x2048][a3:4x4096][a4(queries):4x8192]
__device__ __forceinline__ void decode(int i, int& a, int& b, int& j, int& M) {
  if (i < 32768)      { a = 0; b = i >> 13; j = i & 8191; M = 8192; }
  else if (i < 49152) { int t = i - 32768; a = 1; b = t >> 12; j = t & 4095; M = 4096; }
  else if (i < 57344) { int t = i - 49152; a = 2; b = t >> 11; j = t & 2047; M = 2048; }
  else if (i < 73728) { int t = i - 57344; a = 3; b = t >> 12; j = t & 4095; M = 4096; }
  else                { int t = i - 73728; a = 4; b = t >> 13; j = t & 8191; M = 8192; }
}
__device__ __forceinline__ int seg_ptbase(int a, int b, int M) {
  int ab = (a == 0) ? 0 : ((a == 1) ? 32768 : ((a == 2) ? 49152 : 57344));
  return ab + b * M;
}

// ---------------- build: zero -> hist -> scan(3) -> scatter -----------------
__global__ __launch_bounds__(256) void zero_kernel(uint4* __restrict__ p) {
  int i = blockIdx.x * 256 + threadIdx.x;
  if (i < ZERO_N4) p[i] = make_uint4(0, 0, 0, 0);
}

__global__ __launch_bounds__(256) void grid_hist(
    const float* __restrict__ k2p, const float* __restrict__ k3p,
    const float* __restrict__ k4p, const float* __restrict__ mmp,
    const float* __restrict__ pts, u32* __restrict__ cellEnd) {
  int i = blockIdx.x * 256 + threadIdx.x;
  if (i >= 106496) return;
  int a, b, j, M; decode(i, a, b, j, M);
  const float* src = (a == 0) ? k2p : ((a == 1) ? k3p :
                     ((a == 2) ? k4p : ((a == 3) ? mmp : pts)));
  const float* p = src + ((size_t)b * M + j) * 3;
  float x = p[0], y = p[1], z = p[2];
  if (fabsf(x) < 48.f && fabsf(y) < 48.f && fabsf(z) < 48.f) {
    int cx = min((int)((x - GORG) * GINV), 63);
    int cy = min((int)((y - GORG) * GINV), 63);
    int cz = min((int)((z - GORG) * GINV), 63);
    int seg = (a < 4) ? a * 4 + b : 16 + b;
    atomicAdd(cellEnd + (((size_t)seg) << 18) + ((cz << 12) | (cy << 6) | cx), 1u);
  }
}

// S1: 5120 blocks (20 segs x 256), 1024 cells/block: local exclusive scan
__global__ __launch_bounds__(256) void scan_local(
    u32* __restrict__ cellEnd, u32* __restrict__ blockSums) {
  __shared__ u32 lds[256];
  uint4* c = (uint4*)(cellEnd + ((size_t)(blockIdx.x >> 8) << 18) +
                      ((blockIdx.x & 255) << 10));
  int t = threadIdx.x;
  uint4 v = c[t];                       // coalesced 16B/lane
  u32 ts = v.x + v.y + v.z + v.w;
  lds[t] = ts;
  __syncthreads();
  for (int off = 1; off < 256; off <<= 1) {   // Hillis-Steele inclusive
    u32 a = (t >= off) ? lds[t - off] : 0;
    __syncthreads();
    lds[t] += a;
    __syncthreads();
  }
  u32 ex = t ? lds[t - 1] : 0;
  c[t] = make_uint4(ex, ex + v.x, ex + v.x + v.y, ex + v.x + v.y + v.z);
  if (t == 255) blockSums[blockIdx.x] = lds[255];
}

// S2: 20 blocks: exclusive scan of 256 block sums per segment
__global__ __launch_bounds__(256) void scan_block(u32* __restrict__ blockSums) {
  __shared__ u32 lds[256];
  u32* bs = blockSums + (blockIdx.x << 8);
  int t = threadIdx.x;
  lds[t] = bs[t];
  __syncthreads();
  for (int off = 1; off < 256; off <<= 1) {
    u32 a = (t >= off) ? lds[t - off] : 0;
    __syncthreads();
    lds[t] += a;
    __syncthreads();
  }
  bs[t] = t ? lds[t - 1] : 0;
}

// S3: add scanned block offsets -> cell START values
__global__ __launch_bounds__(256) void scan_add(
    u32* __restrict__ cellEnd, const u32* __restrict__ blockSums) {
  uint4* c = (uint4*)(cellEnd + ((size_t)(blockIdx.x >> 8) << 18) +
                      ((blockIdx.x & 255) << 10));
  u32 off = blockSums[blockIdx.x];
  int t = threadIdx.x;
  uint4 v = c[t];
  c[t] = make_uint4(v.x + off, v.y + off, v.z + off, v.w + off);
}

__global__ __launch_bounds__(256) void grid_scatter(
    const float* __restrict__ k2p, const float* __restrict__ k3p,
    const float* __restrict__ k4p, const float* __restrict__ mmp,
    const float* __restrict__ pts,
    u32* __restrict__ cellEnd, u32* __restrict__ ovfCnt,
    float4* __restrict__ ovfPts, float4* __restrict__ spts,
    float4* __restrict__ qspts) {
  int i = blockIdx.x * 256 + threadIdx.x;
  if (i >= 106496) return;
  int a, b, j, M; decode(i, a, b, j, M);
  const float* src = (a == 0) ? k2p : ((a == 1) ? k3p :
                     ((a == 2) ? k4p : ((a == 3) ? mmp : pts)));
  const float* p = src + ((size_t)b * M + j) * 3;
  float x = p[0], y = p[1], z = p[2];
  int seg = (a < 4) ? a * 4 + b : 16 + b;
  if (fabsf(x) < 48.f && fabsf(y) < 48.f && fabsf(z) < 48.f) {
    int cx = min((int)((x - GORG) * GINV), 63);
    int cy = min((int)((y - GORG) * GINV), 63);
    int cz = min((int)((z - GORG) * GINV), 63);
    u32 pos = atomicAdd(cellEnd + (((size_t)seg) << 18) + ((cz << 12) | (cy << 6) | cx), 1u);
    if (a < 4) spts[seg_ptbase(a, b, M) + pos] = make_float4(x, y, z, __int_as_float(j));
    else       qspts[b * 8192 + pos] = make_float4(x, y, z, __int_as_float(j));
  } else {
    u32 o = atomicAdd(ovfCnt + seg, 1u);
    if (o < OVF_CAP) ovfPts[(seg << 10) + o] = make_float4(x, y, z, __int_as_float(j));
  }
}

// ---------------- grid search + epilogue ------------------------------------
// Queries are processed in cell-sorted order -> all 64 lanes of a wave sit in
// adjacent cells: same rings, shared cache lines, no outlier-tail divergence.
__global__ __launch_bounds__(256, 2) void grid_search(
    const float* __restrict__ pts,
    const float* __restrict__ k2p, const float* __restrict__ f2,
    const float* __restrict__ k3p, const float* __restrict__ f3,
    const float* __restrict__ k4p, const float* __restrict__ f4,
    const float* __restrict__ mmp,
    const float* __restrict__ wfc, const float* __restrict__ wcls,
    const u32* __restrict__ cellEnd, const u32* __restrict__ ovfCnt,
    const float4* __restrict__ ovfPts, const float4* __restrict__ spts,
    const float4* __restrict__ qspts,
    float* __restrict__ out) {
  __shared__ float swv[96];
  __shared__ float spart[64][3];
  __shared__ int   sidx[64];
  const int tid = threadIdx.x;
  const int b = blockIdx.y;
  const int qbase = blockIdx.x * 64;
  const int qi = tid & 63;
  const int task = __builtin_amdgcn_readfirstlane(tid >> 6);  // 0..2 NN, 3 mask

  if (tid >= 64 && tid < 160) {          // fold w_cls @ w_fc
    int t = tid - 64;
    float acc = 0.f;
    for (int j = 0; j < 64; ++j) acc += wcls[j] * wfc[j * 96 + t];
    swv[t] = acc;
  }

  // sorted query sourcing: in-grid sorted first, then query-overflow entries
  const u32 novf_q = min(ovfCnt[16 + b], (u32)OVF_CAP);
  const int N_in = 8192 - (int)novf_q;
  const int e = qbase + qi;
  const float4 qv = (e < N_in) ? qspts[b * 8192 + e]
                               : ovfPts[((16 + b) << 10) + (e - N_in)];
  const float qx = qv.x, qy = qv.y, qz = qv.z;
  const int oi = __float_as_int(qv.w);   // original query index within batch
  if (tid < 64) sidx[tid] = oi;

  const double qdx = (double)qx, qdy = (double)qy, qdz = (double)qz;
  const double qn_d = (qdx * qdx + qdy * qdy) + qdz * qdz;  // ref grouping
  const int cx = min(max((int)((fminf(fmaxf(qx, -48.f), 47.9f) - GORG) * GINV), 0), 63);
  const int cy = min(max((int)((fminf(fmaxf(qy, -48.f), 47.9f) - GORG) * GINV), 0), 63);
  const int cz = min(max((int)((fminf(fmaxf(qz, -48.f), 47.9f) - GORG) * GINV), 0), 63);

  const int Mt[4] = {8192, 4096, 2048, 4096};
  const int seg = task * 4 + b;
  const u32* ce = cellEnd + ((size_t)seg << 18);
  const float4* sp = spts + seg_ptbase(task, b, Mt[task]);
  const float4* op = ovfPts + (seg << 10);
  const u32 oc = min(ovfCnt[seg], (u32)OVF_CAP);

  u64 t6[6];
#pragma unroll
  for (int r = 0; r < 6; ++r) t6[r] = INFKEY;

  if (task < 3) {
    // DIRECT-DISTANCE prefilter key: kv = |q-k|^2 in f32 (err ~1e-5).
    // kv>=0 -> bits monotone, u64-packable; top-6 is the exact min-6 of
    // (key,idx) pairs -> scatter-order independent. f64-rescored downstream.
    auto keyins = [&](float4 c) {
      float dx = qx - c.x, dy = qy - c.y, dz = qz - c.z;
      float kv = fmaf(dz, dz, fmaf(dy, dy, dx * dx));
      u64 kn = ((u64)__float_as_uint(kv) << 32) | (u32)__float_as_uint(c.w);
      if (kn < t6[5]) {
        u64 t;
        t = umax64(t6[0], kn); t6[0] = umin64(t6[0], kn); kn = t;
        t = umax64(t6[1], kn); t6[1] = umin64(t6[1], kn); kn = t;
        t = umax64(t6[2], kn); t6[2] = umin64(t6[2], kn); kn = t;
        t = umax64(t6[3], kn); t6[3] = umin64(t6[3], kn); kn = t;
        t = umax64(t6[4], kn); t6[4] = umin64(t6[4], kn); kn = t;
        t6[5] = umin64(t6[5], kn);
      }
    };
    auto runf = [&](u32 ps, u32 pe) {    // EXACT: no tail padding/duplicates
      u32 p = ps;
      for (; p + 4 <= pe; p += 4) {
        float4 cc[4];
#pragma unroll
        for (int u = 0; u < 4; ++u) cc[u] = sp[p + u];
#pragma unroll
        for (int u = 0; u < 4; ++u) keyins(cc[u]);
      }
      for (; p < pe; ++p) keyins(sp[p]);
    };
    for (u32 o = 0; o < oc; ++o) keyins(op[o]);   // out-of-grid: always scan
    int r = 0;
    while (true) {
      for (int dz = -r; dz <= r; ++dz) {          // shell r only (no revisit)
        int z = cz + dz; if ((unsigned)z > 63u) continue;
        for (int dy = -r; dy <= r; ++dy) {
          int y = cy + dy; if ((unsigned)y > 63u) continue;
          int rb = (z << 12) | (y << 6);
          bool edge = (dz == -r || dz == r || dy == -r || dy == r);
          if (edge) {
            int x0 = max(cx - r, 0), x1 = min(cx + r, 63);
            u32 pe = ce[rb + x1];
            u32 ps = (rb + x0) ? ce[rb + x0 - 1] : 0;
            runf(ps, pe);
          } else {
            int xl = cx - r;
            if (xl >= 0) { u32 pe = ce[rb + xl]; u32 ps = (rb + xl) ? ce[rb + xl - 1] : 0; runf(ps, pe); }
            int xr = cx + r;
            if (xr <= 63) { u32 pe = ce[rb + xr]; u32 ps = ce[rb + xr - 1]; runf(ps, pe); }
          }
        }
      }
      if (r >= 1) {
        // stop: 3rd-best key + margin <= dist^2 to nearest unscanned cell
        float d3f = __uint_as_float((u32)(t6[2] >> 32));   // inf if <3 found
        float m = 1e30f;
        if (cx - r > 0)  m = fminf(m, qx - (GORG + (cx - r) * GH));
        if (cx + r < 63) m = fminf(m, (GORG + (cx + r + 1) * GH) - qx);
        if (cy - r > 0)  m = fminf(m, qy - (GORG + (cy - r) * GH));
        if (cy + r < 63) m = fminf(m, (GORG + (cy + r + 1) * GH) - qy);
        if (cz - r > 0)  m = fminf(m, qz - (GORG + (cz - r) * GH));
        if (cz + r < 63) m = fminf(m, (GORG + (cz + r + 1) * GH) - qz);
        if (m > 0.f && d3f + 0.01f <= m * m) break;
      }
      if (r >= 63) break;
      ++r;
    }
  } else {
    // mask: any point < 0.5 m is within Chebyshev ring 1 (0.5 < GH) -> exact
    const double dm2x = -2.0 * qdx, dm2y = -2.0 * qdy, dm2z = -2.0 * qdz;
    double smin = 1e300;
    auto meval = [&](float4 c) {
      double x = (double)c.x, y = (double)c.y, z = (double)c.z;
      double kn = fma(z, z, fma(y, y, x * x));
      smin = fmin(smin, fma(dm2x, x, fma(dm2y, y, fma(dm2z, z, kn))));
    };
    for (u32 o = 0; o < oc; ++o) meval(op[o]);
    for (int dz = -1; dz <= 1; ++dz) {
      int z = cz + dz; if ((unsigned)z > 63u) continue;
      for (int dy = -1; dy <= 1; ++dy) {
        int y = cy + dy; if ((unsigned)y > 63u) continue;
        int rb = (z << 12) | (y << 6);
        int x0 = max(cx - 1, 0), x1 = min(cx + 1, 63);
        u32 pe = ce[rb + x1];
        u32 ps = (rb + x0) ? ce[rb + x0 - 1] : 0;
        for (u32 p = ps; p < pe; ++p) meval(sp[p]);
      }
    }
    out[NB * NQ + b * NQ + oi] = (qn_d + smin < 0.25) ? 1.0f : 0.0f;
  }
  __syncthreads();

  // epilogue: f64 rescore of top-6 members (ref-exact grouping), weights, FC
  if (tid < 192) {
    const float* kp = (task == 0) ? k2p : ((task == 1) ? k3p : k4p);
    const int    M  = Mt[task];
    double e0 = 1e300, e1 = 1e300, e2 = 1e300;
    int i0 = 0, i1 = 0, i2 = 0;
#pragma unroll
    for (int r = 0; r < 6; ++r) {
      if ((u32)(t6[r] >> 32) == 0x7f800000u) continue;   // skip empty slots
      int idx = (int)(u32)t6[r];
      const float* c = kp + ((size_t)b * M + idx) * 3;
      double x = (double)c[0], y = (double)c[1], z = (double)c[2];
      double kn2 = (x * x + y * y) + z * z;
      double dot = (qdx * x + qdy * y) + qdz * z;
      double d2 = (qn_d + kn2) - 2.0 * dot;
      lexins(e0, e1, e2, i0, i1, i2, d2, idx);
    }
    double d0 = fmax(e0, 0.0), d1 = fmax(e1, 0.0), d2v = fmax(e2, 0.0);
    double r0 = 1.0 / (d0 + 1e-8), r1 = 1.0 / (d1 + 1e-8), r2 = 1.0 / (d2v + 1e-8);
    double sum = (r0 + r1) + r2;
    float wa = (float)(r0 / sum), wb = (float)(r1 / sum), wc = (float)(r2 / sum);
    const float* fp = (task == 0) ? f2 : ((task == 1) ? f3 : f4);
    const float* g0 = fp + ((size_t)b * M + i0) * 32;
    const float* g1 = fp + ((size_t)b * M + i1) * 32;
    const float* g2 = fp + ((size_t)b * M + i2) * 32;
    float acc = 0.f;
#pragma unroll
    for (int wd = 0; wd < 32; ++wd) {
      float v = (wa * g0[wd] + wb * g1[wd]) + wc * g2[wd];
      acc += swv[task * 32 + wd] * v;
    }
    spart[qi][task] = acc;
  }
  __syncthreads();
  if (tid < 64) {
    out[b * NQ + sidx[tid]] =
        (spart[tid][0] + spart[tid][1]) + spart[tid][2];
  }
}

// ---------------- brute fallback (r11-proven structure, no workspace) -------
__device__ __forceinline__ void ins4f(float kv, u32 idx,
                                      float& k0, float& k1, float& k2, float& k3,
                                      u32& i0, u32& i1, u32& i2, u32& i3) {
  if (kv < k3) {
    bool lt0 = kv < k0, lt1 = kv < k1, lt2 = kv < k2;
    k3 = lt2 ? k2 : kv;               i3 = lt2 ? i2 : idx;
    k2 = lt2 ? (lt1 ? k1 : kv) : k2;  i2 = lt2 ? (lt1 ? i1 : idx) : i2;
    k1 = lt1 ? (lt0 ? k0 : kv) : k1;  i1 = lt1 ? (lt0 ? i0 : idx) : i1;
    k0 = lt0 ? kv : k0;               i0 = lt0 ? idx : i0;
  }
}

__global__ __launch_bounds__(512, 2) void brute_kernel(
    const float* __restrict__ pts,
    const float* __restrict__ k2p, const float* __restrict__ f2,
    const float* __restrict__ k3p, const float* __restrict__ f3,
    const float* __restrict__ k4p, const float* __restrict__ f4,
    const float* __restrict__ mmp,
    const float* __restrict__ wfc, const float* __restrict__ wcls,
    float* __restrict__ out) {
  __shared__ double sqn[64];
  __shared__ float dk[3][64][4][4];
  __shared__ u32 di[3][64][4][4];
  __shared__ double mmin[64][8];
  __shared__ float swv[96];
  __shared__ float spart[64][3];
  const int tid = threadIdx.x;
  const int b = blockIdx.y;
  const int q0 = blockIdx.x * 64;
  const int qloc = tid & 63;
  const int wid = __builtin_amdgcn_readfirstlane(tid >> 6);
  if (tid >= 64 && tid < 160) {
    int t = tid - 64;
    float acc = 0.f;
    for (int j = 0; j < 64; ++j) acc += wcls[j] * wfc[j * 96 + t];
    swv[t] = acc;
  }
  int gq = b * NQ + q0 + qloc;
  float qx = pts[3 * gq], qy = pts[3 * gq + 1], qz = pts[3 * gq + 2];
  double qdx = qx, qdy = qy, qdz = qz;
  double qn = (qdx * qdx + qdy * qdy) + qdz * qdz;
  if (tid < 64) sqn[tid] = qn;
  float m2x = -2.f * qx, m2y = -2.f * qy, m2z = -2.f * qz;
  double dm2x = -2.0 * qdx, dm2y = -2.0 * qdy, dm2z = -2.0 * qdz;
  {
    int lvl, prt, gs, gl;
    if (wid < 4)      { lvl = 0; prt = wid;     gs = wid * 2048;       gl = 2048; }
    else if (wid < 6) { lvl = 1; prt = wid - 4; gs = (wid - 4) * 2048; gl = 2048; }
    else              { lvl = 2; prt = wid - 6; gs = (wid - 6) * 1024; gl = 1024; }
    const float* raw = ((lvl == 0) ? k2p : ((lvl == 1) ? k3p : k4p)) +
                       (size_t)b * ((lvl == 0) ? 8192 : ((lvl == 1) ? 4096 : 2048)) * 3;
    float k0 = __builtin_inff(), k1 = k0, k2 = k0, k3 = k0;
    u32 i0 = 0, i1 = 0, i2 = 0, i3 = 0;
    for (int j = 0; j < gl; j += 8) {
      float key[8];
#pragma unroll
      for (int u = 0; u < 8; ++u) {
        const float* p = raw + (size_t)(gs + j + u) * 3;
        float x = p[0], y = p[1], z = p[2];
        float n2 = fmaf(z, z, fmaf(y, y, x * x));
        key[u] = fmaf(m2x, x, fmaf(m2y, y, fmaf(m2z, z, n2)));
      }
#pragma unroll
      for (int u = 0; u < 8; ++u)
        ins4f(key[u], (u32)(gs + j + u), k0, k1, k2, k3, i0, i1, i2, i3);
    }
    dk[lvl][qloc][prt][0] = k0; di[lvl][qloc][prt][0] = i0;
    dk[lvl][qloc][prt][1] = k1; di[lvl][qloc][prt][1] = i1;
    dk[lvl][qloc][prt][2] = k2; di[lvl][qloc][prt][2] = i2;
    dk[lvl][qloc][prt][3] = k3; di[lvl][qloc][prt][3] = i3;
    int ms = (wid < 6) ? wid * 256 : 1536 + (wid - 6) * 1280;
    int ml = (wid < 6) ? 256 : 1280;
    const float* mr = mmp + (size_t)b * 4096 * 3;
    double smin = 1e300;
    for (int j = 0; j < ml; ++j) {
      const float* p = mr + (size_t)(ms + j) * 3;
      double x = p[0], y = p[1], z = p[2];
      double kn = fma(z, z, fma(y, y, x * x));
      smin = fmin(smin, fma(dm2x, x, fma(dm2y, y, fma(dm2z, z, kn))));
    }
    mmin[qloc][wid] = smin;
  }
  __syncthreads();
  if (tid < 192) {
    int lvl = __builtin_amdgcn_readfirstlane(tid >> 6);
    int q = tid & 63;
    const float* kp = (lvl == 0) ? k2p : ((lvl == 1) ? k3p : k4p);
    int M = (lvl == 0) ? 8192 : ((lvl == 1) ? 4096 : 2048);
    int np = (lvl == 0) ? 4 : 2;
    double qn2 = sqn[q];
    const float* qp2 = pts + 3 * (b * NQ + q0 + q);
    double ax = qp2[0], ay = qp2[1], az = qp2[2];
    double e0 = 1e300, e1 = 1e300, e2 = 1e300;
    int i0 = 0, i1 = 0, i2 = 0;
    for (int h = 0; h < np; ++h)
#pragma unroll
      for (int r = 0; r < 4; ++r) {
        int idx = (int)di[lvl][q][h][r];
        const float* c = kp + ((size_t)b * M + idx) * 3;
        double x = c[0], y = c[1], z = c[2];
        double kn2 = (x * x + y * y) + z * z;
        double dot = (ax * x + ay * y) + az * z;
        lexins(e0, e1, e2, i0, i1, i2, (qn2 + kn2) - 2.0 * dot, idx);
      }
    double d0 = fmax(e0, 0.0), d1 = fmax(e1, 0.0), d2v = fmax(e2, 0.0);
    double r0 = 1.0 / (d0 + 1e-8), r1 = 1.0 / (d1 + 1e-8), r2 = 1.0 / (d2v + 1e-8);
    double sum = (r0 + r1) + r2;
    float wa = (float)(r0 / sum), wb = (float)(r1 / sum), wc = (float)(r2 / sum);
    const float* fp = (lvl == 0) ? f2 : ((lvl == 1) ? f3 : f4);
    const float* g0 = fp + ((size_t)b * M + i0) * 32;
    const float* g1 = fp + ((size_t)b * M + i1) * 32;
    const float* g2 = fp + ((size_t)b * M + i2) * 32;
    float acc = 0.f;
#pragma unroll
    for (int wd = 0; wd < 32; ++wd)
      acc += swv[lvl * 32 + wd] * ((wa * g0[wd] + wb * g1[wd]) + wc * g2[wd]);
    spart[q][lvl] = acc;
  } else if (tid < 256) {
    int q = tid - 192;
    double sm = mmin[q][0];
#pragma unroll
    for (int p = 1; p < 8; ++p) sm = fmin(sm, mmin[q][p]);
    out[NB * NQ + b * NQ + q0 + q] = (sqn[q] + sm < 0.25) ? 1.0f : 0.0f;
  }
  __syncthreads();
  if (tid < 64)
    out[b * NQ + q0 + tid] = (spart[tid][0] + spart[tid][1]) + spart[tid][2];
}

extern "C" void kernel_launch(void* const* d_in, const int* in_sizes, int n_in,
                              void* d_out, int out_size, void* d_ws, size_t ws_size,
                              hipStream_t stream) {
  const float* pts    = (const float*)d_in[0];
  const float* known2 = (const float*)d_in[1];
  const float* feats2 = (const float*)d_in[2];
  const float* known3 = (const float*)d_in[3];
  const float* feats3 = (const float*)d_in[4];
  const float* known4 = (const float*)d_in[5];
  const float* feats4 = (const float*)d_in[6];
  const float* match  = (const float*)d_in[7];
  const float* wfc    = (const float*)d_in[8];
  const float* wcls   = (const float*)d_in[9];

  if (ws_size >= WS_GRID) {
    char* ws = (char*)d_ws;
    u32*    cellEnd   = (u32*)ws;
    u32*    ovfCnt    = (u32*)(ws + OFF_OVC);
    u32*    blockSums = (u32*)(ws + OFF_BS);
    float4* ovfPts    = (float4*)(ws + OFF_OVP);
    float4* spts      = (float4*)(ws + OFF_SP);
    float4* qspts     = (float4*)(ws + OFF_QP);
    hipLaunchKernelGGL(zero_kernel, dim3(5121), dim3(256), 0, stream, (uint4*)ws);
    hipLaunchKernelGGL(grid_hist, dim3(416), dim3(256), 0, stream,
                       known2, known3, known4, match, pts, cellEnd);
    hipLaunchKernelGGL(scan_local, dim3(5120), dim3(256), 0, stream,
                       cellEnd, blockSums);
    hipLaunchKernelGGL(scan_block, dim3(20), dim3(256), 0, stream, blockSums);
    hipLaunchKernelGGL(scan_add, dim3(5120), dim3(256), 0, stream,
                       cellEnd, blockSums);
    hipLaunchKernelGGL(grid_scatter, dim3(416), dim3(256), 0, stream,
                       known2, known3, known4, match, pts,
                       cellEnd, ovfCnt, ovfPts, spts, qspts);
    hipLaunchKernelGGL(grid_search, dim3(128, NB), dim3(256), 0, stream,
                       pts, known2, feats2, known3, feats3, known4, feats4,
                       match, wfc, wcls, cellEnd, ovfCnt, ovfPts, spts, qspts,
                       (float*)d_out);
  } else {
    hipLaunchKernelGGL(brute_kernel, dim3(128, NB), dim3(512), 0, stream,
                       pts, known2, feats2, known3, feats3, known4, feats4,
                       match, wfc, wcls, (float*)d_out);
  }
}

// Round 16
// 1690.185 us; speedup vs baseline: 1.3737x; 1.3525x over previous
//
#include <hip/hip_runtime.h>

typedef unsigned int       u32;
typedef unsigned long long u64;

#define NB 4
#define NQ 8192
#define GH   1.5f
#define GINV (1.0f/1.5f)
#define GORG (-48.0f)
#define OVF_CAP 1024
#define RMAX 3
// grid-path ws layout (bytes): 20 segs = 16 candidate + 4 query
#define OFF_OVC 20971520ull                 // cellEnd: 20 * 262144 * 4
#define OFF_BS  20971648ull                 // ovfCnt 80B (+pad)
#define OFF_OVP 20992128ull                 // blockSums 5120*4
#define OFF_SP  21319808ull                 // ovfPts 20*1024*16
#define OFF_QP  22499456ull                 // spts 73728*16
#define WS_GRID 23023744ull                 // qspts 32768*16
#define ZERO_N4 1310728                     // (cellEnd+ovfCnt)/16
#define INFKEY  (0x7f800000ULL << 32)

__device__ __forceinline__ u64 umin64(u64 a, u64 b) { return a < b ? a : b; }
__device__ __forceinline__ u64 umax64(u64 a, u64 b) { return a > b ? a : b; }

// lexicographic (d, idx) insert into sorted triple; ties -> lower index.
// NOTE: does NOT reject duplicates — caller must never insert the same
// (d,idx) twice (r15 bug: ring+brute double-insert corrupted e1/e2).
__device__ __forceinline__ void lexins(double& e0d, double& e1d, double& e2d,
                                       int& e0i, int& e1i, int& e2i,
                                       double d, int i) {
  if (d < e2d || (d == e2d && i < e2i)) {
    if (d < e0d || (d == e0d && i < e0i)) {
      e2d = e1d; e2i = e1i; e1d = e0d; e1i = e0i; e0d = d; e0i = i;
    } else if (d < e1d || (d == e1d && i < e1i)) {
      e2d = e1d; e2i = e1i; e1d = d; e1i = i;
    } else {
      e2d = d; e2i = i;
    }
  }
}

// item decode: [a0:4x8192][a1:4x4096][a2:4x2048][a3:4x4096][a4(queries):4x8192]
__device__ __forceinline__ void decode(int i, int& a, int& b, int& j, int& M) {
  if (i < 32768)      { a = 0; b = i >> 13; j = i & 8191; M = 8192; }
  else if (i < 49152) { int t = i - 32768; a = 1; b = t >> 12; j = t & 4095; M = 4096; }
  else if (i < 57344) { int t = i - 49152; a = 2; b = t >> 11; j = t & 2047; M = 2048; }
  else if (i < 73728) { int t = i - 57344; a = 3; b = t >> 12; j = t & 4095; M = 4096; }
  else                { int t = i - 73728; a = 4; b = t >> 13; j = t & 8191; M = 8192; }
}
__device__ __forceinline__ int seg_ptbase(int a, int b, int M) {
  int ab = (a == 0) ? 0 : ((a == 1) ? 32768 : ((a == 2) ? 49152 : 57344));
  return ab + b * M;
}

// ---------------- build: zero -> hist -> scan(3) -> scatter -----------------
__global__ __launch_bounds__(256) void zero_kernel(uint4* __restrict__ p) {
  int i = blockIdx.x * 256 + threadIdx.x;
  if (i < ZERO_N4) p[i] = make_uint4(0, 0, 0, 0);
}

__global__ __launch_bounds__(256) void grid_hist(
    const float* __restrict__ k2p, const float* __restrict__ k3p,
    const float* __restrict__ k4p, const float* __restrict__ mmp,
    const float* __restrict__ pts, u32* __restrict__ cellEnd) {
  int i = blockIdx.x * 256 + threadIdx.x;
  if (i >= 106496) return;
  int a, b, j, M; decode(i, a, b, j, M);
  const float* src = (a == 0) ? k2p : ((a == 1) ? k3p :
                     ((a == 2) ? k4p : ((a == 3) ? mmp : pts)));
  const float* p = src + ((size_t)b * M + j) * 3;
  float x = p[0], y = p[1], z = p[2];
  if (fabsf(x) < 48.f && fabsf(y) < 48.f && fabsf(z) < 48.f) {
    int cx = min((int)((x - GORG) * GINV), 63);
    int cy = min((int)((y - GORG) * GINV), 63);
    int cz = min((int)((z - GORG) * GINV), 63);
    int seg = (a < 4) ? a * 4 + b : 16 + b;
    atomicAdd(cellEnd + (((size_t)seg) << 18) + ((cz << 12) | (cy << 6) | cx), 1u);
  }
}

// S1: 5120 blocks (20 segs x 256), 1024 cells/block: local exclusive scan
__global__ __launch_bounds__(256) void scan_local(
    u32* __restrict__ cellEnd, u32* __restrict__ blockSums) {
  __shared__ u32 lds[256];
  uint4* c = (uint4*)(cellEnd + ((size_t)(blockIdx.x >> 8) << 18) +
                      ((blockIdx.x & 255) << 10));
  int t = threadIdx.x;
  uint4 v = c[t];                       // coalesced 16B/lane
  u32 ts = v.x + v.y + v.z + v.w;
  lds[t] = ts;
  __syncthreads();
  for (int off = 1; off < 256; off <<= 1) {   // Hillis-Steele inclusive
    u32 a = (t >= off) ? lds[t - off] : 0;
    __syncthreads();
    lds[t] += a;
    __syncthreads();
  }
  u32 ex = t ? lds[t - 1] : 0;
  c[t] = make_uint4(ex, ex + v.x, ex + v.x + v.y, ex + v.x + v.y + v.z);
  if (t == 255) blockSums[blockIdx.x] = lds[255];
}

// S2: 20 blocks: exclusive scan of 256 block sums per segment
__global__ __launch_bounds__(256) void scan_block(u32* __restrict__ blockSums) {
  __shared__ u32 lds[256];
  u32* bs = blockSums + (blockIdx.x << 8);
  int t = threadIdx.x;
  lds[t] = bs[t];
  __syncthreads();
  for (int off = 1; off < 256; off <<= 1) {
    u32 a = (t >= off) ? lds[t - off] : 0;
    __syncthreads();
    lds[t] += a;
    __syncthreads();
  }
  bs[t] = t ? lds[t - 1] : 0;
}

// S3: add scanned block offsets -> cell START values
__global__ __launch_bounds__(256) void scan_add(
    u32* __restrict__ cellEnd, const u32* __restrict__ blockSums) {
  uint4* c = (uint4*)(cellEnd + ((size_t)(blockIdx.x >> 8) << 18) +
                      ((blockIdx.x & 255) << 10));
  u32 off = blockSums[blockIdx.x];
  int t = threadIdx.x;
  uint4 v = c[t];
  c[t] = make_uint4(v.x + off, v.y + off, v.z + off, v.w + off);
}

__global__ __launch_bounds__(256) void grid_scatter(
    const float* __restrict__ k2p, const float* __restrict__ k3p,
    const float* __restrict__ k4p, const float* __restrict__ mmp,
    const float* __restrict__ pts,
    u32* __restrict__ cellEnd, u32* __restrict__ ovfCnt,
    float4* __restrict__ ovfPts, float4* __restrict__ spts,
    float4* __restrict__ qspts) {
  int i = blockIdx.x * 256 + threadIdx.x;
  if (i >= 106496) return;
  int a, b, j, M; decode(i, a, b, j, M);
  const float* src = (a == 0) ? k2p : ((a == 1) ? k3p :
                     ((a == 2) ? k4p : ((a == 3) ? mmp : pts)));
  const float* p = src + ((size_t)b * M + j) * 3;
  float x = p[0], y = p[1], z = p[2];
  int seg = (a < 4) ? a * 4 + b : 16 + b;
  if (fabsf(x) < 48.f && fabsf(y) < 48.f && fabsf(z) < 48.f) {
    int cx = min((int)((x - GORG) * GINV), 63);
    int cy = min((int)((y - GORG) * GINV), 63);
    int cz = min((int)((z - GORG) * GINV), 63);
    u32 pos = atomicAdd(cellEnd + (((size_t)seg) << 18) + ((cz << 12) | (cy << 6) | cx), 1u);
    if (a < 4) spts[seg_ptbase(a, b, M) + pos] = make_float4(x, y, z, __int_as_float(j));
    else       qspts[b * 8192 + pos] = make_float4(x, y, z, __int_as_float(j));
  } else {
    u32 o = atomicAdd(ovfCnt + seg, 1u);
    if (o < OVF_CAP) ovfPts[(seg << 10) + o] = make_float4(x, y, z, __int_as_float(j));
  }
}

// ---------------- grid search + epilogue ------------------------------------
// Queries processed in cell-sorted order (lane coherence); ring radius capped
// at RMAX. Unconverged lanes RESET their top-6 and brute-scan the whole
// segment (in-grid + overflow) so every candidate enters the multiset
// exactly once — no duplicates (the r15 bug).
__global__ __launch_bounds__(256, 2) void grid_search(
    const float* __restrict__ pts,
    const float* __restrict__ k2p, const float* __restrict__ f2,
    const float* __restrict__ k3p, const float* __restrict__ f3,
    const float* __restrict__ k4p, const float* __restrict__ f4,
    const float* __restrict__ mmp,
    const float* __restrict__ wfc, const float* __restrict__ wcls,
    const u32* __restrict__ cellEnd, const u32* __restrict__ ovfCnt,
    const float4* __restrict__ ovfPts, const float4* __restrict__ spts,
    const float4* __restrict__ qspts,
    float* __restrict__ out) {
  __shared__ float swv[96];
  __shared__ float spart[64][3];
  __shared__ int   sidx[64];
  const int tid = threadIdx.x;
  const int b = blockIdx.y;
  const int qbase = blockIdx.x * 64;
  const int qi = tid & 63;
  const int task = __builtin_amdgcn_readfirstlane(tid >> 6);  // 0..2 NN, 3 mask

  if (tid >= 64 && tid < 160) {          // fold w_cls @ w_fc
    int t = tid - 64;
    float acc = 0.f;
    for (int j = 0; j < 64; ++j) acc += wcls[j] * wfc[j * 96 + t];
    swv[t] = acc;
  }

  // sorted query sourcing: in-grid sorted first, then query-overflow entries
  const u32 novf_q = min(ovfCnt[16 + b], (u32)OVF_CAP);
  const int N_in = 8192 - (int)novf_q;
  const int e = qbase + qi;
  const float4 qv = (e < N_in) ? qspts[b * 8192 + e]
                               : ovfPts[((16 + b) << 10) + (e - N_in)];
  const float qx = qv.x, qy = qv.y, qz = qv.z;
  const int oi = __float_as_int(qv.w);   // original query index within batch
  if (tid < 64) sidx[tid] = oi;

  const double qdx = (double)qx, qdy = (double)qy, qdz = (double)qz;
  const double qn_d = (qdx * qdx + qdy * qdy) + qdz * qdz;  // ref grouping
  const int cx = min(max((int)((fminf(fmaxf(qx, -48.f), 47.9f) - GORG) * GINV), 0), 63);
  const int cy = min(max((int)((fminf(fmaxf(qy, -48.f), 47.9f) - GORG) * GINV), 0), 63);
  const int cz = min(max((int)((fminf(fmaxf(qz, -48.f), 47.9f) - GORG) * GINV), 0), 63);

  const int Mt[4] = {8192, 4096, 2048, 4096};
  const int seg = task * 4 + b;
  const u32* ce = cellEnd + ((size_t)seg << 18);
  const float4* sp = spts + seg_ptbase(task, b, Mt[task]);
  const float4* op = ovfPts + (seg << 10);
  const u32 oc = min(ovfCnt[seg], (u32)OVF_CAP);

  u64 t6[6];
#pragma unroll
  for (int r = 0; r < 6; ++r) t6[r] = INFKEY;

  if (task < 3) {
    // DIRECT-DISTANCE prefilter key kv = |q-k|^2 (f32, err ~1e-5); kv>=0 ->
    // bits monotone, u64-packed with idx. Top-6 = exact min-6 of the
    // (key,idx) multiset (order-independent); f64-rescored downstream.
    auto keyins = [&](float4 c) {
      float dx = qx - c.x, dy = qy - c.y, dz = qz - c.z;
      float kv = fmaf(dz, dz, fmaf(dy, dy, dx * dx));
      u64 kn = ((u64)__float_as_uint(kv) << 32) | (u32)__float_as_uint(c.w);
      if (kn < t6[5]) {
        u64 t;
        t = umax64(t6[0], kn); t6[0] = umin64(t6[0], kn); kn = t;
        t = umax64(t6[1], kn); t6[1] = umin64(t6[1], kn); kn = t;
        t = umax64(t6[2], kn); t6[2] = umin64(t6[2], kn); kn = t;
        t = umax64(t6[3], kn); t6[3] = umin64(t6[3], kn); kn = t;
        t = umax64(t6[4], kn); t6[4] = umin64(t6[4], kn); kn = t;
        t6[5] = umin64(t6[5], kn);
      }
    };
    auto runf = [&](u32 ps, u32 pe) {    // EXACT: no tail padding/duplicates
      u32 p = ps;
      for (; p + 4 <= pe; p += 4) {
        float4 cc[4];
#pragma unroll
        for (int u = 0; u < 4; ++u) cc[u] = sp[p + u];
#pragma unroll
        for (int u = 0; u < 4; ++u) keyins(cc[u]);
      }
      for (; p < pe; ++p) keyins(sp[p]);
    };
    for (u32 o = 0; o < oc; ++o) keyins(op[o]);   // out-of-grid: always scan
    bool conv = false;
    int r = 0;
    while (true) {
      for (int dz = -r; dz <= r; ++dz) {          // shell r only (no revisit)
        int z = cz + dz; if ((unsigned)z > 63u) continue;
        for (int dy = -r; dy <= r; ++dy) {
          int y = cy + dy; if ((unsigned)y > 63u) continue;
          int rb = (z << 12) | (y << 6);
          bool edge = (dz == -r || dz == r || dy == -r || dy == r);
          if (edge) {
            int x0 = max(cx - r, 0), x1 = min(cx + r, 63);
            u32 pe = ce[rb + x1];
            u32 ps = (rb + x0) ? ce[rb + x0 - 1] : 0;
            runf(ps, pe);
          } else {
            int xl = cx - r;
            if (xl >= 0) { u32 pe = ce[rb + xl]; u32 ps = (rb + xl) ? ce[rb + xl - 1] : 0; runf(ps, pe); }
            int xr = cx + r;
            if (xr <= 63) { u32 pe = ce[rb + xr]; u32 ps = ce[rb + xr - 1]; runf(ps, pe); }
          }
        }
      }
      if (r >= 1) {
        // stop: 3rd-best key + margin <= dist^2 to nearest unscanned cell
        float d3f = __uint_as_float((u32)(t6[2] >> 32));   // inf if <3 found
        float m = 1e30f;
        if (cx - r > 0)  m = fminf(m, qx - (GORG + (cx - r) * GH));
        if (cx + r < 63) m = fminf(m, (GORG + (cx + r + 1) * GH) - qx);
        if (cy - r > 0)  m = fminf(m, qy - (GORG + (cy - r) * GH));
        if (cy + r < 63) m = fminf(m, (GORG + (cy + r + 1) * GH) - qy);
        if (cz - r > 0)  m = fminf(m, qz - (GORG + (cz - r) * GH));
        if (cz + r < 63) m = fminf(m, (GORG + (cz + r + 1) * GH) - qz);
        if (m > 0.f && d3f + 0.01f <= m * m) { conv = true; break; }
      }
      if (r >= RMAX) break;
      ++r;
    }
    // wave-level brute fallback for unconverged lanes: RESET the top-6
    // (dropping ring results) and scan the ENTIRE segment — in-grid points
    // once each, then the overflow points once each. Every distinct
    // candidate enters the multiset exactly once -> exact top-6.
    if (__any(!conv)) {
      const bool need = !conv;
      if (need) {
#pragma unroll
        for (int r2 = 0; r2 < 6; ++r2) t6[r2] = INFKEY;
      }
      const u32 nseg = ce[0x3ffff];     // total in-grid points of segment
      u32 p = 0;
      for (; p + 8 <= nseg; p += 8) {
        float4 cc[8];
#pragma unroll
        for (int u = 0; u < 8; ++u) cc[u] = sp[p + u];
        if (need) {
#pragma unroll
          for (int u = 0; u < 8; ++u) keyins(cc[u]);
        }
      }
      for (; p < nseg; ++p) { float4 c = sp[p]; if (need) keyins(c); }
      for (u32 o = 0; o < oc; ++o) { float4 c = op[o]; if (need) keyins(c); }
    }
  } else {
    // mask: any point < 0.5 m is within Chebyshev ring 1 (0.5 < GH) -> exact
    const double dm2x = -2.0 * qdx, dm2y = -2.0 * qdy, dm2z = -2.0 * qdz;
    double smin = 1e300;
    auto meval = [&](float4 c) {
      double x = (double)c.x, y = (double)c.y, z = (double)c.z;
      double kn = fma(z, z, fma(y, y, x * x));
      smin = fmin(smin, fma(dm2x, x, fma(dm2y, y, fma(dm2z, z, kn))));
    };
    for (u32 o = 0; o < oc; ++o) meval(op[o]);
    for (int dz = -1; dz <= 1; ++dz) {
      int z = cz + dz; if ((unsigned)z > 63u) continue;
      for (int dy = -1; dy <= 1; ++dy) {
        int y = cy + dy; if ((unsigned)y > 63u) continue;
        int rb = (z << 12) | (y << 6);
        int x0 = max(cx - 1, 0), x1 = min(cx + 1, 63);
        u32 pe = ce[rb + x1];
        u32 ps = (rb + x0) ? ce[rb + x0 - 1] : 0;
        for (u32 p = ps; p < pe; ++p) meval(sp[p]);
      }
    }
    out[NB * NQ + b * NQ + oi] = (qn_d + smin < 0.25) ? 1.0f : 0.0f;
  }
  __syncthreads();

  // epilogue: f64 rescore of top-6 members (ref-exact grouping), weights, FC
  if (tid < 192) {
    const float* kp = (task == 0) ? k2p : ((task == 1) ? k3p : k4p);
    const int    M  = Mt[task];
    double e0 = 1e300, e1 = 1e300, e2 = 1e300;
    int i0 = 0, i1 = 0, i2 = 0;
#pragma unroll
    for (int r = 0; r < 6; ++r) {
      if ((u32)(t6[r] >> 32) == 0x7f800000u) continue;   // skip empty slots
      int idx = (int)(u32)t6[r];
      const float* c = kp + ((size_t)b * M + idx) * 3;
      double x = (double)c[0], y = (double)c[1], z = (double)c[2];
      double kn2 = (x * x + y * y) + z * z;
      double dot = (qdx * x + qdy * y) + qdz * z;
      double d2 = (qn_d + kn2) - 2.0 * dot;
      lexins(e0, e1, e2, i0, i1, i2, d2, idx);
    }
    double d0 = fmax(e0, 0.0), d1 = fmax(e1, 0.0), d2v = fmax(e2, 0.0);
    double r0 = 1.0 / (d0 + 1e-8), r1 = 1.0 / (d1 + 1e-8), r2 = 1.0 / (d2v + 1e-8);
    double sum = (r0 + r1) + r2;
    float wa = (float)(r0 / sum), wb = (float)(r1 / sum), wc = (float)(r2 / sum);
    const float* fp = (task == 0) ? f2 : ((task == 1) ? f3 : f4);
    const float* g0 = fp + ((size_t)b * M + i0) * 32;
    const float* g1 = fp + ((size_t)b * M + i1) * 32;
    const float* g2 = fp + ((size_t)b * M + i2) * 32;
    float acc = 0.f;
#pragma unroll
    for (int wd = 0; wd < 32; ++wd) {
      float v = (wa * g0[wd] + wb * g1[wd]) + wc * g2[wd];
      acc += swv[task * 32 + wd] * v;
    }
    spart[qi][task] = acc;
  }
  __syncthreads();
  if (tid < 64) {
    out[b * NQ + sidx[tid]] =
        (spart[tid][0] + spart[tid][1]) + spart[tid][2];
  }
}

// ---------------- brute fallback (r11-proven structure, no workspace) -------
__device__ __forceinline__ void ins4f(float kv, u32 idx,
                                      float& k0, float& k1, float& k2, float& k3,
                                      u32& i0, u32& i1, u32& i2, u32& i3) {
  if (kv < k3) {
    bool lt0 = kv < k0, lt1 = kv < k1, lt2 = kv < k2;
    k3 = lt2 ? k2 : kv;               i3 = lt2 ? i2 : idx;
    k2 = lt2 ? (lt1 ? k1 : kv) : k2;  i2 = lt2 ? (lt1 ? i1 : idx) : i2;
    k1 = lt1 ? (lt0 ? k0 : kv) : k1;  i1 = lt1 ? (lt0 ? i0 : idx) : i1;
    k0 = lt0 ? kv : k0;               i0 = lt0 ? idx : i0;
  }
}

__global__ __launch_bounds__(512, 2) void brute_kernel(
    const float* __restrict__ pts,
    const float* __restrict__ k2p, const float* __restrict__ f2,
    const float* __restrict__ k3p, const float* __restrict__ f3,
    const float* __restrict__ k4p, const float* __restrict__ f4,
    const float* __restrict__ mmp,
    const float* __restrict__ wfc, const float* __restrict__ wcls,
    float* __restrict__ out) {
  __shared__ double sqn[64];
  __shared__ float dk[3][64][4][4];
  __shared__ u32 di[3][64][4][4];
  __shared__ double mmin[64][8];
  __shared__ float swv[96];
  __shared__ float spart[64][3];
  const int tid = threadIdx.x;
  const int b = blockIdx.y;
  const int q0 = blockIdx.x * 64;
  const int qloc = tid & 63;
  const int wid = __builtin_amdgcn_readfirstlane(tid >> 6);
  if (tid >= 64 && tid < 160) {
    int t = tid - 64;
    float acc = 0.f;
    for (int j = 0; j < 64; ++j) acc += wcls[j] * wfc[j * 96 + t];
    swv[t] = acc;
  }
  int gq = b * NQ + q0 + qloc;
  float qx = pts[3 * gq], qy = pts[3 * gq + 1], qz = pts[3 * gq + 2];
  double qdx = qx, qdy = qy, qdz = qz;
  double qn = (qdx * qdx + qdy * qdy) + qdz * qdz;
  if (tid < 64) sqn[tid] = qn;
  float m2x = -2.f * qx, m2y = -2.f * qy, m2z = -2.f * qz;
  double dm2x = -2.0 * qdx, dm2y = -2.0 * qdy, dm2z = -2.0 * qdz;
  {
    int lvl, prt, gs, gl;
    if (wid < 4)      { lvl = 0; prt = wid;     gs = wid * 2048;       gl = 2048; }
    else if (wid < 6) { lvl = 1; prt = wid - 4; gs = (wid - 4) * 2048; gl = 2048; }
    else              { lvl = 2; prt = wid - 6; gs = (wid - 6) * 1024; gl = 1024; }
    const float* raw = ((lvl == 0) ? k2p : ((lvl == 1) ? k3p : k4p)) +
                       (size_t)b * ((lvl == 0) ? 8192 : ((lvl == 1) ? 4096 : 2048)) * 3;
    float k0 = __builtin_inff(), k1 = k0, k2 = k0, k3 = k0;
    u32 i0 = 0, i1 = 0, i2 = 0, i3 = 0;
    for (int j = 0; j < gl; j += 8) {
      float key[8];
#pragma unroll
      for (int u = 0; u < 8; ++u) {
        const float* p = raw + (size_t)(gs + j + u) * 3;
        float x = p[0], y = p[1], z = p[2];
        float n2 = fmaf(z, z, fmaf(y, y, x * x));
        key[u] = fmaf(m2x, x, fmaf(m2y, y, fmaf(m2z, z, n2)));
      }
#pragma unroll
      for (int u = 0; u < 8; ++u)
        ins4f(key[u], (u32)(gs + j + u), k0, k1, k2, k3, i0, i1, i2, i3);
    }
    dk[lvl][qloc][prt][0] = k0; di[lvl][qloc][prt][0] = i0;
    dk[lvl][qloc][prt][1] = k1; di[lvl][qloc][prt][1] = i1;
    dk[lvl][qloc][prt][2] = k2; di[lvl][qloc][prt][2] = i2;
    dk[lvl][qloc][prt][3] = k3; di[lvl][qloc][prt][3] = i3;
    int ms = (wid < 6) ? wid * 256 : 1536 + (wid - 6) * 1280;
    int ml = (wid < 6) ? 256 : 1280;
    const float* mr = mmp + (size_t)b * 4096 * 3;
    double smin = 1e300;
    for (int j = 0; j < ml; ++j) {
      const float* p = mr + (size_t)(ms + j) * 3;
      double x = p[0], y = p[1], z = p[2];
      double kn = fma(z, z, fma(y, y, x * x));
      smin = fmin(smin, fma(dm2x, x, fma(dm2y, y, fma(dm2z, z, kn))));
    }
    mmin[qloc][wid] = smin;
  }
  __syncthreads();
  if (tid < 192) {
    int lvl = __builtin_amdgcn_readfirstlane(tid >> 6);
    int q = tid & 63;
    const float* kp = (lvl == 0) ? k2p : ((lvl == 1) ? k3p : k4p);
    int M = (lvl == 0) ? 8192 : ((lvl == 1) ? 4096 : 2048);
    int np = (lvl == 0) ? 4 : 2;
    double qn2 = sqn[q];
    const float* qp2 = pts + 3 * (b * NQ + q0 + q);
    double ax = qp2[0], ay = qp2[1], az = qp2[2];
    double e0 = 1e300, e1 = 1e300, e2 = 1e300;
    int i0 = 0, i1 = 0, i2 = 0;
    for (int h = 0; h < np; ++h)
#pragma unroll
      for (int r = 0; r < 4; ++r) {
        int idx = (int)di[lvl][q][h][r];
        const float* c = kp + ((size_t)b * M + idx) * 3;
        double x = c[0], y = c[1], z = c[2];
        double kn2 = (x * x + y * y) + z * z;
        double dot = (ax * x + ay * y) + az * z;
        lexins(e0, e1, e2, i0, i1, i2, (qn2 + kn2) - 2.0 * dot, idx);
      }
    double d0 = fmax(e0, 0.0), d1 = fmax(e1, 0.0), d2v = fmax(e2, 0.0);
    double r0 = 1.0 / (d0 + 1e-8), r1 = 1.0 / (d1 + 1e-8), r2 = 1.0 / (d2v + 1e-8);
    double sum = (r0 + r1) + r2;
    float wa = (float)(r0 / sum), wb = (float)(r1 / sum), wc = (float)(r2 / sum);
    const float* fp = (lvl == 0) ? f2 : ((lvl == 1) ? f3 : f4);
    const float* g0 = fp + ((size_t)b * M + i0) * 32;
    const float* g1 = fp + ((size_t)b * M + i1) * 32;
    const float* g2 = fp + ((size_t)b * M + i2) * 32;
    float acc = 0.f;
#pragma unroll
    for (int wd = 0; wd < 32; ++wd)
      acc += swv[lvl * 32 + wd] * ((wa * g0[wd] + wb * g1[wd]) + wc * g2[wd]);
    spart[q][lvl] = acc;
  } else if (tid < 256) {
    int q = tid - 192;
    double sm = mmin[q][0];
#pragma unroll
    for (int p = 1; p < 8; ++p) sm = fmin(sm, mmin[q][p]);
    out[NB * NQ + b * NQ + q0 + q] = (sqn[q] + sm < 0.25) ? 1.0f : 0.0f;
  }
  __syncthreads();
  if (tid < 64)
    out[b * NQ + q0 + tid] = (spart[tid][0] + spart[tid][1]) + spart[tid][2];
}

extern "C" void kernel_launch(void* const* d_in, const int* in_sizes, int n_in,
                              void* d_out, int out_size, void* d_ws, size_t ws_size,
                              hipStream_t stream) {
  const float* pts    = (const float*)d_in[0];
  const float* known2 = (const float*)d_in[1];
  const float* feats2 = (const float*)d_in[2];
  const float* known3 = (const float*)d_in[3];
  const float* feats3 = (const float*)d_in[4];
  const float* known4 = (const float*)d_in[5];
  const float* feats4 = (const float*)d_in[6];
  const float* match  = (const float*)d_in[7];
  const float* wfc    = (const float*)d_in[8];
  const float* wcls   = (const float*)d_in[9];

  if (ws_size >= WS_GRID) {
    char* ws = (char*)d_ws;
    u32*    cellEnd   = (u32*)ws;
    u32*    ovfCnt    = (u32*)(ws + OFF_OVC);
    u32*    blockSums = (u32*)(ws + OFF_BS);
    float4* ovfPts    = (float4*)(ws + OFF_OVP);
    float4* spts      = (float4*)(ws + OFF_SP);
    float4* qspts     = (float4*)(ws + OFF_QP);
    hipLaunchKernelGGL(zero_kernel, dim3(5121), dim3(256), 0, stream, (uint4*)ws);
    hipLaunchKernelGGL(grid_hist, dim3(416), dim3(256), 0, stream,
                       known2, known3, known4, match, pts, cellEnd);
    hipLaunchKernelGGL(scan_local, dim3(5120), dim3(256), 0, stream,
                       cellEnd, blockSums);
    hipLaunchKernelGGL(scan_block, dim3(20), dim3(256), 0, stream, blockSums);
    hipLaunchKernelGGL(scan_add, dim3(5120), dim3(256), 0, stream,
                       cellEnd, blockSums);
    hipLaunchKernelGGL(grid_scatter, dim3(416), dim3(256), 0, stream,
                       known2, known3, known4, match, pts,
                       cellEnd, ovfCnt, ovfPts, spts, qspts);
    hipLaunchKernelGGL(grid_search, dim3(128, NB), dim3(256), 0, stream,
                       pts, known2, feats2, known3, feats3, known4, feats4,
                       match, wfc, wcls, cellEnd, ovfCnt, ovfPts, spts, qspts,
                       (float*)d_out);
  } else {
    hipLaunchKernelGGL(brute_kernel, dim3(128, NB), dim3(512), 0, stream,
                       pts, known2, feats2, known3, feats3, known4, feats4,
                       match, wfc, wcls, (float*)d_out);
  }
}